// Round 10
// baseline (263.605 us; speedup 1.0000x reference)
//
#include <hip/hip_runtime.h>
#include <hip/hip_bf16.h>
#include <stdint.h>

#define Q_NUM   2000000
#define T_NUM   200000
#define T_CURVE 20000
#define NF      8
#define NH      64
#define NOUT    3

// ws byte layout:
//   [0     .. 20479   ]  weight fragments (5120 dwords)          (validated r4/r5)
//   [32768 .. +25.6MB ]  per-triangle records: 8 x float4 each   (validated r8)
#define WS_REC_OFF   32768
#define WS_NEEDED    (WS_REC_OFF + (size_t)T_NUM * 128)

#define NWSF 5120   // dwords of weight fragments

typedef float f32x16 __attribute__((ext_vector_type(16)));
typedef short s16x8  __attribute__((ext_vector_type(8)));

union FragU { int4 v; s16x8 s; unsigned u[4]; };

__device__ __forceinline__ unsigned short f2bf(float f) {
    __hip_bfloat16 h = __float2bfloat16(f);   // RNE
    unsigned short u; __builtin_memcpy(&u, &h, 2); return u;
}
__device__ __forceinline__ float bf2f(unsigned short u) {
    unsigned v = ((unsigned)u) << 16; float f; __builtin_memcpy(&f, &v, 4); return f;
}

// ================= setup kernel (validated r4/r5) =================
__global__ void prep_w(const float* __restrict__ w1, const float* __restrict__ b1,
                       const float* __restrict__ w2, unsigned* __restrict__ wsf) {
    const int l = threadIdx.x;  // 64 threads
    if (l >= 64) return;
    const int hb = l >> 5;
    for (int plane = 0; plane < 2; ++plane)
      for (int kb = 0; kb < 4; ++kb)
        for (int mb = 0; mb < 2; ++mb)
          for (int i = 0; i < 4; ++i) {
              const int j  = 32 * mb + (l & 31);
              const int k0 = 16 * kb + 8 * hb + 2 * i;
              const float v0 = w2[k0 * NH + j];
              const float v1 = w2[(k0 + 1) * NH + j];
              unsigned d;
              if (plane == 0) {
                  d = (unsigned)f2bf(v0) | ((unsigned)f2bf(v1) << 16);
              } else {
                  const float r0 = v0 - bf2f(f2bf(v0));
                  const float r1 = v1 - bf2f(f2bf(v1));
                  d = (unsigned)f2bf(r0) | ((unsigned)f2bf(r1) << 16);
              }
              wsf[(((plane * 4 + kb) * 2 + mb) * 64 + l) * 4 + i] = d;
          }
    for (int plane = 0; plane < 2; ++plane)
      for (int mb = 0; mb < 2; ++mb)
        for (int i = 0; i < 4; ++i) {
            const int j = 32 * mb + (l & 31);
            unsigned d = 0;
            if (hb == 0) {
                const int k0 = 2 * i;
                const float v0 = w1[k0 * NH + j];
                const float v1 = w1[(k0 + 1) * NH + j];
                if (plane == 0) {
                    d = (unsigned)f2bf(v0) | ((unsigned)f2bf(v1) << 16);
                } else {
                    const float r0 = v0 - bf2f(f2bf(v0));
                    const float r1 = v1 - bf2f(f2bf(v1));
                    d = (unsigned)f2bf(r0) | ((unsigned)f2bf(r1) << 16);
                }
            } else if (i == 0) {
                const float bv = b1[j];
                if (plane == 0) {
                    d = (unsigned)f2bf(bv);
                } else {
                    d = (unsigned)f2bf(bv - bf2f(f2bf(bv)));
                }
            }
            wsf[4096 + ((plane * 2 + mb) * 64 + l) * 4 + i] = d;
        }
}

// ================= per-triangle record builder (validated r8) =================
__global__ __launch_bounds__(256) void build_rec(
    const float* __restrict__ Vcont,
    const float* __restrict__ Vdisc,
    const float* __restrict__ Vcurv,
    const int*   __restrict__ T,
    const void*  __restrict__ VisCont,
    const int*   __restrict__ Tadj,
    const void*  __restrict__ Tsign,
    const int*   __restrict__ seco,
    float4* __restrict__ rec)
{
    const uint32_t* probe = (const uint32_t*)VisCont;
    uint32_t m = 0;
#pragma unroll
    for (int i = 0; i < 16; ++i) m |= probe[i];
    const bool bool_is_byte = (m > 1u);

    const int t = blockIdx.x * blockDim.x + threadIdx.x;
    if (t >= T_NUM) return;

    const int tv0 = T[t * 3 + 0];
    const int tv1 = T[t * 3 + 1];
    const int tv2 = T[t * 3 + 2];

    int d0 = Tadj[t * 6 + 0];
    int d1 = Tadj[t * 6 + 2];
    int d2 = Tadj[t * 6 + 4];

    const bool is_curved = (t < T_CURVE);
    if (is_curved) {
        const int s0 = seco[t * 2 + 0];
        const int s1 = seco[t * 2 + 1];
        if (s0 >= 0) d1 = s0;
        if (s1 >= 0) d2 = s1;
    }

    auto rdbool = [&](const void* p, int idx) -> bool {
        return bool_is_byte ? (((const uint8_t*)p)[idx] != 0)
                            : (((const int*)p)[idx] != 0);
    };

    const bool use0 = (!rdbool(VisCont, tv0)) && (d0 >= 0);
    const bool use1 = (!rdbool(VisCont, tv1)) && (d1 >= 0);
    const bool use2 = (!rdbool(VisCont, tv2)) && (d2 >= 0);

    const float4* c0p = (const float4*)(use0 ? &Vdisc[(size_t)d0 * NF] : &Vcont[(size_t)tv0 * NF]);
    const float4* c1p = (const float4*)(use1 ? &Vdisc[(size_t)d1 * NF] : &Vcont[(size_t)tv1 * NF]);
    const float4* c2p = (const float4*)(use2 ? &Vdisc[(size_t)d2 * NF] : &Vcont[(size_t)tv2 * NF]);

    float4* rp = &rec[(size_t)t * 8];
    rp[0] = c0p[0]; rp[1] = c0p[1];
    rp[2] = c1p[0]; rp[3] = c1p[1];
    rp[4] = c2p[0]; rp[5] = c2p[1];

    float4 cv0 = make_float4(0.f, 0.f, 0.f, 0.f);
    float4 cv1 = cv0;
    if (is_curved) {
        const float s = rdbool(Tsign, t) ? 1.0f : -1.0f;
        const float4* cvp = (const float4*)&Vcurv[(size_t)t * NF];
        float4 a = cvp[0], b = cvp[1];
        cv0 = make_float4(s * a.x, s * a.y, s * a.z, s * a.w);
        cv1 = make_float4(s * b.x, s * b.y, s * b.z, s * b.w);
    }
    rp[6] = cv0; rp[7] = cv1;
}

// ================= low-pressure fused MLP for one 32-query block =================
// Identical math to validated r8/r9 mlp_block; the layer-3 fold uses
// compile-time table indices (wave-uniform s_loads) with hb value-selects
// (r4-validated pattern) instead of per-lane indexed VMEM loads.
__device__ __forceinline__ void mlp_block(const unsigned src[4], bool hb, int lane,
                                          const unsigned* slds,
                                          const float* __restrict__ b2,
                                          const float* __restrict__ w3,
                                          float& p0, float& p1, float& p2)
{
    FragU fb;
    fb.u[0] = hb ? 0x00003F80u : src[0];   // hi lanes: 1.0 in bias slot k=8
    fb.u[1] = hb ? 0u : src[1];
    fb.u[2] = hb ? 0u : src[2];
    fb.u[3] = hb ? 0u : src[3];

    // ---- layer 1, mb-sequential ----
    unsigned pk[8][2];
#pragma unroll
    for (int mb = 0; mb < 2; ++mb) {
        FragU a1hi, a1lo;
        a1hi.v = *(const int4*)&slds[4096 + ((0 * 2 + mb) * 64 + lane) * 4];
        a1lo.v = *(const int4*)&slds[4096 + ((1 * 2 + mb) * 64 + lane) * 4];
        f32x16 accA;
#pragma unroll
        for (int z = 0; z < 16; ++z) accA[z] = 0.f;
        accA = __builtin_amdgcn_mfma_f32_32x32x16_bf16(a1hi.s, fb.s, accA, 0, 0, 0);
        accA = __builtin_amdgcn_mfma_f32_32x32x16_bf16(a1lo.s, fb.s, accA, 0, 0, 0);
#pragma unroll
        for (int hh = 0; hh < 4; ++hh) {
            const int rb = 4 * hh;
            const float v0 = fmaxf(accA[rb + 0], 0.f);
            const float v1 = fmaxf(accA[rb + 1], 0.f);
            const float v2 = fmaxf(accA[rb + 2], 0.f);
            const float v3 = fmaxf(accA[rb + 3], 0.f);
            pk[4 * mb + hh][0] = (unsigned)f2bf(v0) | ((unsigned)f2bf(v1) << 16);
            pk[4 * mb + hh][1] = (unsigned)f2bf(v2) | ((unsigned)f2bf(v3) << 16);
        }
    }

    // ---- build all four B2 fragments once ----
    FragU fr[4];
#pragma unroll
    for (int kb = 0; kb < 4; ++kb) {
        const unsigned own0 = hb ? pk[2 * kb + 1][0] : pk[2 * kb][0];
        const unsigned own1 = hb ? pk[2 * kb + 1][1] : pk[2 * kb][1];
        const unsigned X0   = hb ? pk[2 * kb][0] : pk[2 * kb + 1][0];
        const unsigned X1   = hb ? pk[2 * kb][1] : pk[2 * kb + 1][1];
        const unsigned Y0   = (unsigned)__shfl_xor((int)X0, 32);
        const unsigned Y1   = (unsigned)__shfl_xor((int)X1, 32);
        fr[kb].u[0] = hb ? Y0 : own0;
        fr[kb].u[1] = hb ? Y1 : own1;
        fr[kb].u[2] = hb ? own0 : Y0;
        fr[kb].u[3] = hb ? own1 : Y1;
    }

    // ---- layer 2 + layer-3 partial, mb-sequential ----
    // All table indices are compile-time constants -> wave-uniform s_loads;
    // hb picks between the two candidate VALUES (1 v_cndmask each).
#pragma unroll
    for (int mb = 0; mb < 2; ++mb) {
        f32x16 acc;
#pragma unroll
        for (int z = 0; z < 16; ++z) acc[z] = 0.f;
#pragma unroll
        for (int kb = 0; kb < 4; ++kb) {
            FragU ahi, alo;
            ahi.v = *(const int4*)&slds[(((0 * 4 + kb) * 2 + mb) * 64 + lane) * 4];
            alo.v = *(const int4*)&slds[(((1 * 4 + kb) * 2 + mb) * 64 + lane) * 4];
            acc = __builtin_amdgcn_mfma_f32_32x32x16_bf16(ahi.s, fr[kb].s, acc, 0, 0, 0);
            acc = __builtin_amdgcn_mfma_f32_32x32x16_bf16(alo.s, fr[kb].s, acc, 0, 0, 0);
        }
#pragma unroll
        for (int r = 0; r < 16; ++r) {
            const int jr = (r & 3) + 8 * (r >> 2) + 32 * mb;   // compile-time
            const float b2v = hb ? b2[jr + 4]          : b2[jr];
            const float w30 = hb ? w3[(jr + 4) * 3 + 0] : w3[jr * 3 + 0];
            const float w31 = hb ? w3[(jr + 4) * 3 + 1] : w3[jr * 3 + 1];
            const float w32 = hb ? w3[(jr + 4) * 3 + 2] : w3[jr * 3 + 2];
            const float tv = fmaxf(acc[r] + b2v, 0.f);
            p0 = fmaf(tv, w30, p0);
            p1 = fmaf(tv, w31, p1);
            p2 = fmaf(tv, w32, p2);
        }
    }
}

// ================= main kernel =================
template <bool REC>
__global__ __launch_bounds__(256) void dann_fwd_t(
    const float* __restrict__ QT_uv,
    const float* __restrict__ Vcont,
    const float* __restrict__ Vdisc,
    const float* __restrict__ Vcurv,
    const float* __restrict__ b2,
    const float* __restrict__ w3, const float* __restrict__ b3,
    const int*   __restrict__ T,
    const int*   __restrict__ QT_idx,
    const void*  __restrict__ VisCont,
    const int*   __restrict__ Tadj,
    const void*  __restrict__ Tsign,
    const int*   __restrict__ seco,
    const unsigned* __restrict__ wsf,
    const float4* __restrict__ rec,
    float* __restrict__ out)
{
    __shared__ unsigned slds[NWSF];
    // stage weight fragments into LDS (coalesced; rec traffic can't thrash LDS)
    for (int i = threadIdx.x; i < NWSF; i += 256) slds[i] = wsf[i];

    const int q  = blockIdx.x * blockDim.x + threadIdx.x;
    const int qc = (q < Q_NUM) ? q : (Q_NUM - 1);   // clamp loads; store guarded below
    const int  lane    = threadIdx.x & 63;
    const bool hb      = (lane >= 32);
    const bool lo_half = !hb;

    const float2 uv = ((const float2*)QT_uv)[qc];
    const float u  = uv.x;
    const float v  = uv.y;
    const float w0 = 1.0f - u - v;
    const int   t  = QT_idx[qc];
    const float bub = 27.0f * w0 * u * v;

    float4 c0a, c0b, c1a, c1b, c2a, c2b, cva, cvb;
    float cf;

    if (REC) {
        const float4* rp = &rec[(size_t)t * 8];
        c0a = rp[0]; c0b = rp[1];
        c1a = rp[2]; c1b = rp[3];
        c2a = rp[4]; c2b = rp[5];
        cva = rp[6]; cvb = rp[7];
        cf = bub;                      // sign / is_curved folded into cva/cvb
    } else {
        const uint32_t* probe = (const uint32_t*)VisCont;
        uint32_t m = 0;
#pragma unroll
        for (int i = 0; i < 16; ++i) m |= probe[i];
        const bool bool_is_byte = (m > 1u);

        const int tv0 = T[t * 3 + 0];
        const int tv1 = T[t * 3 + 1];
        const int tv2 = T[t * 3 + 2];
        int d0 = Tadj[t * 6 + 0];
        int d1 = Tadj[t * 6 + 2];
        int d2 = Tadj[t * 6 + 4];
        const bool is_curved = (t < T_CURVE);
        const int  cid = is_curved ? t : (T_CURVE - 1);
        const int  s0 = seco[cid * 2 + 0];
        const int  s1 = seco[cid * 2 + 1];
        if (is_curved && s0 >= 0) d1 = s0;
        if (is_curved && s1 >= 0) d2 = s1;
        auto rdbool = [&](const void* p, int i) -> bool {
            return bool_is_byte ? (((const uint8_t*)p)[i] != 0)
                                : (((const int*)p)[i] != 0);
        };
        const bool use0 = (!rdbool(VisCont, tv0)) && (d0 >= 0);
        const bool use1 = (!rdbool(VisCont, tv1)) && (d1 >= 0);
        const bool use2 = (!rdbool(VisCont, tv2)) && (d2 >= 0);
        const float4* c0p = (const float4*)(use0 ? &Vdisc[(size_t)d0 * NF] : &Vcont[(size_t)tv0 * NF]);
        const float4* c1p = (const float4*)(use1 ? &Vdisc[(size_t)d1 * NF] : &Vcont[(size_t)tv1 * NF]);
        const float4* c2p = (const float4*)(use2 ? &Vdisc[(size_t)d2 * NF] : &Vcont[(size_t)tv2 * NF]);
        c0a = c0p[0]; c0b = c0p[1];
        c1a = c1p[0]; c1b = c1p[1];
        c2a = c2p[0]; c2b = c2p[1];
        cf = 0.0f;
        if (is_curved) cf = rdbool(Tsign, cid) ? bub : -bub;
        const float4* cvp = (const float4*)&Vcurv[(size_t)cid * NF];
        cva = cvp[0]; cvb = cvp[1];
    }

    float feat[NF];
    {
        const float* a0 = (const float*)&c0a;  const float* bb0 = (const float*)&c0b;
        const float* a1 = (const float*)&c1a;  const float* bb1 = (const float*)&c1b;
        const float* a2 = (const float*)&c2a;  const float* bb2 = (const float*)&c2b;
        const float* av = (const float*)&cva;  const float* bv  = (const float*)&cvb;
#pragma unroll
        for (int f = 0; f < 4; ++f) {
            feat[f]     = w0 * a0[f]  + u * a1[f]  + v * a2[f]  + cf * av[f];
            feat[f + 4] = w0 * bb0[f] + u * bb1[f] + v * bb2[f] + cf * bv[f];
        }
    }

    unsigned pf[4];
#pragma unroll
    for (int i = 0; i < 4; ++i)
        pf[i] = (unsigned)f2bf(feat[2 * i]) | ((unsigned)f2bf(feat[2 * i + 1]) << 16);

    __syncthreads();   // slds ready

    // ---- half A: queries 0..31 ----
    float pA0 = 0.f, pA1 = 0.f, pA2 = 0.f;
    mlp_block(pf, hb, lane, slds, b2, w3, pA0, pA1, pA2);

    // ---- half B: queries 32..63 ----
    unsigned pfx[4];
#pragma unroll
    for (int i = 0; i < 4; ++i) pfx[i] = (unsigned)__shfl_xor((int)pf[i], 32);
    float pB0 = 0.f, pB1 = 0.f, pB2 = 0.f;
    mlp_block(pfx, hb, lane, slds, b2, w3, pB0, pB1, pB2);

    // ---- combine (validated r4/r6 epilogue) ----
    const float sA0 = pA0 + __shfl_xor(pA0, 32);
    const float sA1 = pA1 + __shfl_xor(pA1, 32);
    const float sA2 = pA2 + __shfl_xor(pA2, 32);
    const float sB0 = pB0 + __shfl_xor(pB0, 32);
    const float sB1 = pB1 + __shfl_xor(pB1, 32);
    const float sB2 = pB2 + __shfl_xor(pB2, 32);

    const float o0 = (lo_half ? sA0 : sB0) + b3[0];
    const float o1 = (lo_half ? sA1 : sB1) + b3[1];
    const float o2 = (lo_half ? sA2 : sB2) + b3[2];

    if (q < Q_NUM) {
        const size_t off = (size_t)q * NOUT;
        out[off + 0] = o0;
        out[off + 1] = o1;
        out[off + 2] = o2;
    }
}

extern "C" void kernel_launch(void* const* d_in, const int* in_sizes, int n_in,
                              void* d_out, int out_size, void* d_ws, size_t ws_size,
                              hipStream_t stream) {
    const float* QT_uv  = (const float*)d_in[2];
    const float* Vcont  = (const float*)d_in[3];
    const float* Vdisc  = (const float*)d_in[4];
    const float* Vcurv  = (const float*)d_in[5];
    const float* w1     = (const float*)d_in[6];
    const float* b1     = (const float*)d_in[7];
    const float* w2     = (const float*)d_in[8];
    const float* b2     = (const float*)d_in[9];
    const float* w3     = (const float*)d_in[10];
    const float* b3     = (const float*)d_in[11];
    const int*   T      = (const int*)d_in[12];
    const int*   QT_idx = (const int*)d_in[13];
    const void*  VisC   = d_in[14];
    const int*   Tadj   = (const int*)d_in[15];
    const void*  Tsign  = d_in[16];
    const int*   seco   = (const int*)d_in[17];
    float* out = (float*)d_out;

    unsigned* wsf = (unsigned*)d_ws;
    prep_w<<<1, 64, 0, stream>>>(w1, b1, w2, wsf);

    const int block = 256;
    const int grid  = (Q_NUM + block - 1) / block;

    if (ws_size >= WS_NEEDED) {
        float4* rec = (float4*)((char*)d_ws + WS_REC_OFF);
        build_rec<<<(T_NUM + 255) / 256, 256, 0, stream>>>(Vcont, Vdisc, Vcurv,
                                                           T, VisC, Tadj, Tsign, seco, rec);
        dann_fwd_t<true><<<grid, block, 0, stream>>>(QT_uv, Vcont, Vdisc, Vcurv,
                                                     b2, w3, b3,
                                                     T, QT_idx, VisC, Tadj, Tsign, seco,
                                                     wsf, rec, out);
    } else {
        dann_fwd_t<false><<<grid, block, 0, stream>>>(QT_uv, Vcont, Vdisc, Vcurv,
                                                      b2, w3, b3,
                                                      T, QT_idx, VisC, Tadj, Tsign, seco,
                                                      wsf, (const float4*)nullptr, out);
    }
}

// Round 11
// 117.319 us; speedup vs baseline: 2.2469x; 2.2469x over previous
//
#include <hip/hip_runtime.h>
#include <hip/hip_bf16.h>
#include <stdint.h>

#define Q_NUM   2000000
#define T_NUM   200000
#define T_CURVE 20000
#define NF      8
#define NH      64
#define NOUT    3

// ws byte layout:
//   [0     .. 21503   ]  weight fragments (5120 dwords) + epilogue table (256 dwords)
//   [32768 .. +25.6MB ]  per-triangle records: 8 x float4 each   (validated r8)
#define WS_REC_OFF   32768
#define WS_NEEDED    (WS_REC_OFF + (size_t)T_NUM * 128)

#define NWSF_W  5120   // dwords of weight fragments
#define NWSF    5376   // + 64 float4 epilogue table

typedef float f32x16 __attribute__((ext_vector_type(16)));
typedef short s16x8  __attribute__((ext_vector_type(8)));

union FragU { int4 v; s16x8 s; unsigned u[4]; };

__device__ __forceinline__ unsigned short f2bf(float f) {
    __hip_bfloat16 h = __float2bfloat16(f);   // RNE
    unsigned short u; __builtin_memcpy(&u, &h, 2); return u;
}
__device__ __forceinline__ float bf2f(unsigned short u) {
    unsigned v = ((unsigned)u) << 16; float f; __builtin_memcpy(&f, &v, 4); return f;
}

// ================= setup kernel (validated r4/r5; + epilogue table) =================
__global__ void prep_w(const float* __restrict__ w1, const float* __restrict__ b1,
                       const float* __restrict__ w2, const float* __restrict__ b2,
                       const float* __restrict__ w3, unsigned* __restrict__ wsf) {
    const int l = threadIdx.x;  // 64 threads
    if (l >= 64) return;
    const int hb = l >> 5;
    for (int plane = 0; plane < 2; ++plane)
      for (int kb = 0; kb < 4; ++kb)
        for (int mb = 0; mb < 2; ++mb)
          for (int i = 0; i < 4; ++i) {
              const int j  = 32 * mb + (l & 31);
              const int k0 = 16 * kb + 8 * hb + 2 * i;
              const float v0 = w2[k0 * NH + j];
              const float v1 = w2[(k0 + 1) * NH + j];
              unsigned d;
              if (plane == 0) {
                  d = (unsigned)f2bf(v0) | ((unsigned)f2bf(v1) << 16);
              } else {
                  const float r0 = v0 - bf2f(f2bf(v0));
                  const float r1 = v1 - bf2f(f2bf(v1));
                  d = (unsigned)f2bf(r0) | ((unsigned)f2bf(r1) << 16);
              }
              wsf[(((plane * 4 + kb) * 2 + mb) * 64 + l) * 4 + i] = d;
          }
    for (int plane = 0; plane < 2; ++plane)
      for (int mb = 0; mb < 2; ++mb)
        for (int i = 0; i < 4; ++i) {
            const int j = 32 * mb + (l & 31);
            unsigned d = 0;
            if (hb == 0) {
                const int k0 = 2 * i;
                const float v0 = w1[k0 * NH + j];
                const float v1 = w1[(k0 + 1) * NH + j];
                if (plane == 0) {
                    d = (unsigned)f2bf(v0) | ((unsigned)f2bf(v1) << 16);
                } else {
                    const float r0 = v0 - bf2f(f2bf(v0));
                    const float r1 = v1 - bf2f(f2bf(v1));
                    d = (unsigned)f2bf(r0) | ((unsigned)f2bf(r1) << 16);
                }
            } else if (i == 0) {
                const float bv = b1[j];
                if (plane == 0) {
                    d = (unsigned)f2bf(bv);
                } else {
                    d = (unsigned)f2bf(bv - bf2f(f2bf(bv)));
                }
            }
            wsf[NWSF_W - 1024 + ((plane * 2 + mb) * 64 + l) * 4 + i] = d;
        }
    // epilogue table: ep[j] = { b2[j], w3[j][0], w3[j][1], w3[j][2] }
    float4* ep = (float4*)&wsf[NWSF_W];
    ep[l] = make_float4(b2[l], w3[l * 3 + 0], w3[l * 3 + 1], w3[l * 3 + 2]);
}

// ================= per-triangle record builder (validated r8) =================
__global__ __launch_bounds__(256) void build_rec(
    const float* __restrict__ Vcont,
    const float* __restrict__ Vdisc,
    const float* __restrict__ Vcurv,
    const int*   __restrict__ T,
    const void*  __restrict__ VisCont,
    const int*   __restrict__ Tadj,
    const void*  __restrict__ Tsign,
    const int*   __restrict__ seco,
    float4* __restrict__ rec)
{
    const uint32_t* probe = (const uint32_t*)VisCont;
    uint32_t m = 0;
#pragma unroll
    for (int i = 0; i < 16; ++i) m |= probe[i];
    const bool bool_is_byte = (m > 1u);

    const int t = blockIdx.x * blockDim.x + threadIdx.x;
    if (t >= T_NUM) return;

    const int tv0 = T[t * 3 + 0];
    const int tv1 = T[t * 3 + 1];
    const int tv2 = T[t * 3 + 2];

    int d0 = Tadj[t * 6 + 0];
    int d1 = Tadj[t * 6 + 2];
    int d2 = Tadj[t * 6 + 4];

    const bool is_curved = (t < T_CURVE);
    if (is_curved) {
        const int s0 = seco[t * 2 + 0];
        const int s1 = seco[t * 2 + 1];
        if (s0 >= 0) d1 = s0;
        if (s1 >= 0) d2 = s1;
    }

    auto rdbool = [&](const void* p, int idx) -> bool {
        return bool_is_byte ? (((const uint8_t*)p)[idx] != 0)
                            : (((const int*)p)[idx] != 0);
    };

    const bool use0 = (!rdbool(VisCont, tv0)) && (d0 >= 0);
    const bool use1 = (!rdbool(VisCont, tv1)) && (d1 >= 0);
    const bool use2 = (!rdbool(VisCont, tv2)) && (d2 >= 0);

    const float4* c0p = (const float4*)(use0 ? &Vdisc[(size_t)d0 * NF] : &Vcont[(size_t)tv0 * NF]);
    const float4* c1p = (const float4*)(use1 ? &Vdisc[(size_t)d1 * NF] : &Vcont[(size_t)tv1 * NF]);
    const float4* c2p = (const float4*)(use2 ? &Vdisc[(size_t)d2 * NF] : &Vcont[(size_t)tv2 * NF]);

    float4* rp = &rec[(size_t)t * 8];
    rp[0] = c0p[0]; rp[1] = c0p[1];
    rp[2] = c1p[0]; rp[3] = c1p[1];
    rp[4] = c2p[0]; rp[5] = c2p[1];

    float4 cv0 = make_float4(0.f, 0.f, 0.f, 0.f);
    float4 cv1 = cv0;
    if (is_curved) {
        const float s = rdbool(Tsign, t) ? 1.0f : -1.0f;
        const float4* cvp = (const float4*)&Vcurv[(size_t)t * NF];
        float4 a = cvp[0], b = cvp[1];
        cv0 = make_float4(s * a.x, s * a.y, s * a.z, s * a.w);
        cv1 = make_float4(s * b.x, s * b.y, s * b.z, s * b.w);
    }
    rp[6] = cv0; rp[7] = cv1;
}

// ================= low-pressure fused MLP for one 32-query block =================
// Identical math to validated r9/r10 mlp_block; layer-3 fold reads the packed
// epilogue table from LDS (base+immediate ds_read_b128, read-at-use).
__device__ __forceinline__ void mlp_block(const unsigned src[4], bool hb, int lane,
                                          const unsigned* slds, const float4* epb,
                                          float& p0, float& p1, float& p2)
{
    FragU fb;
    fb.u[0] = hb ? 0x00003F80u : src[0];   // hi lanes: 1.0 in bias slot k=8
    fb.u[1] = hb ? 0u : src[1];
    fb.u[2] = hb ? 0u : src[2];
    fb.u[3] = hb ? 0u : src[3];

    // ---- layer 1, mb-sequential ----
    unsigned pk[8][2];
#pragma unroll
    for (int mb = 0; mb < 2; ++mb) {
        FragU a1hi, a1lo;
        a1hi.v = *(const int4*)&slds[NWSF_W - 1024 + ((0 * 2 + mb) * 64 + lane) * 4];
        a1lo.v = *(const int4*)&slds[NWSF_W - 1024 + ((1 * 2 + mb) * 64 + lane) * 4];
        f32x16 accA;
#pragma unroll
        for (int z = 0; z < 16; ++z) accA[z] = 0.f;
        accA = __builtin_amdgcn_mfma_f32_32x32x16_bf16(a1hi.s, fb.s, accA, 0, 0, 0);
        accA = __builtin_amdgcn_mfma_f32_32x32x16_bf16(a1lo.s, fb.s, accA, 0, 0, 0);
#pragma unroll
        for (int hh = 0; hh < 4; ++hh) {
            const int rb = 4 * hh;
            const float v0 = fmaxf(accA[rb + 0], 0.f);
            const float v1 = fmaxf(accA[rb + 1], 0.f);
            const float v2 = fmaxf(accA[rb + 2], 0.f);
            const float v3 = fmaxf(accA[rb + 3], 0.f);
            pk[4 * mb + hh][0] = (unsigned)f2bf(v0) | ((unsigned)f2bf(v1) << 16);
            pk[4 * mb + hh][1] = (unsigned)f2bf(v2) | ((unsigned)f2bf(v3) << 16);
        }
    }

    // ---- build all four B2 fragments once ----
    FragU fr[4];
#pragma unroll
    for (int kb = 0; kb < 4; ++kb) {
        const unsigned own0 = hb ? pk[2 * kb + 1][0] : pk[2 * kb][0];
        const unsigned own1 = hb ? pk[2 * kb + 1][1] : pk[2 * kb][1];
        const unsigned X0   = hb ? pk[2 * kb][0] : pk[2 * kb + 1][0];
        const unsigned X1   = hb ? pk[2 * kb][1] : pk[2 * kb + 1][1];
        const unsigned Y0   = (unsigned)__shfl_xor((int)X0, 32);
        const unsigned Y1   = (unsigned)__shfl_xor((int)X1, 32);
        fr[kb].u[0] = hb ? Y0 : own0;
        fr[kb].u[1] = hb ? Y1 : own1;
        fr[kb].u[2] = hb ? own0 : Y0;
        fr[kb].u[3] = hb ? own1 : Y1;
    }

    // ---- layer 2 + layer-3 partial, mb-sequential ----
#pragma unroll
    for (int mb = 0; mb < 2; ++mb) {
        f32x16 acc;
#pragma unroll
        for (int z = 0; z < 16; ++z) acc[z] = 0.f;
#pragma unroll
        for (int kb = 0; kb < 4; ++kb) {
            FragU ahi, alo;
            ahi.v = *(const int4*)&slds[(((0 * 4 + kb) * 2 + mb) * 64 + lane) * 4];
            alo.v = *(const int4*)&slds[(((1 * 4 + kb) * 2 + mb) * 64 + lane) * 4];
            acc = __builtin_amdgcn_mfma_f32_32x32x16_bf16(ahi.s, fr[kb].s, acc, 0, 0, 0);
            acc = __builtin_amdgcn_mfma_f32_32x32x16_bf16(alo.s, fr[kb].s, acc, 0, 0, 0);
        }
        // fold: ds_read_b128 at base (epb, hb folded in) + compile-time offset
#pragma unroll
        for (int r = 0; r < 16; ++r) {
            const int jr = (r & 3) + 8 * (r >> 2) + 32 * mb;   // compile-time
            const float4 e = epb[jr];                          // {b2, w3[0..2]}
            const float tv = fmaxf(acc[r] + e.x, 0.f);
            p0 = fmaf(tv, e.y, p0);
            p1 = fmaf(tv, e.z, p1);
            p2 = fmaf(tv, e.w, p2);
        }
    }
}

// ================= main kernel =================
template <bool REC>
__global__ __launch_bounds__(256) void dann_fwd_t(
    const float* __restrict__ QT_uv,
    const float* __restrict__ Vcont,
    const float* __restrict__ Vdisc,
    const float* __restrict__ Vcurv,
    const float* __restrict__ b3,
    const int*   __restrict__ T,
    const int*   __restrict__ QT_idx,
    const void*  __restrict__ VisCont,
    const int*   __restrict__ Tadj,
    const void*  __restrict__ Tsign,
    const int*   __restrict__ seco,
    const unsigned* __restrict__ wsf,
    const float4* __restrict__ rec,
    float* __restrict__ out)
{
    __shared__ unsigned slds[NWSF];
    for (int i = threadIdx.x; i < NWSF; i += 256) slds[i] = wsf[i];

    const int q  = blockIdx.x * blockDim.x + threadIdx.x;
    const int qc = (q < Q_NUM) ? q : (Q_NUM - 1);   // clamp loads; store guarded below
    const int  lane    = threadIdx.x & 63;
    const bool hb      = (lane >= 32);
    const bool lo_half = !hb;

    const float2 uv = ((const float2*)QT_uv)[qc];
    const float u  = uv.x;
    const float v  = uv.y;
    const float w0 = 1.0f - u - v;
    const int   t  = QT_idx[qc];
    const float bub = 27.0f * w0 * u * v;

    float4 c0a, c0b, c1a, c1b, c2a, c2b, cva, cvb;
    float cf;

    if (REC) {
        const float4* rp = &rec[(size_t)t * 8];
        c0a = rp[0]; c0b = rp[1];
        c1a = rp[2]; c1b = rp[3];
        c2a = rp[4]; c2b = rp[5];
        cva = rp[6]; cvb = rp[7];
        cf = bub;                      // sign / is_curved folded into cva/cvb
    } else {
        const uint32_t* probe = (const uint32_t*)VisCont;
        uint32_t m = 0;
#pragma unroll
        for (int i = 0; i < 16; ++i) m |= probe[i];
        const bool bool_is_byte = (m > 1u);

        const int tv0 = T[t * 3 + 0];
        const int tv1 = T[t * 3 + 1];
        const int tv2 = T[t * 3 + 2];
        int d0 = Tadj[t * 6 + 0];
        int d1 = Tadj[t * 6 + 2];
        int d2 = Tadj[t * 6 + 4];
        const bool is_curved = (t < T_CURVE);
        const int  cid = is_curved ? t : (T_CURVE - 1);
        const int  s0 = seco[cid * 2 + 0];
        const int  s1 = seco[cid * 2 + 1];
        if (is_curved && s0 >= 0) d1 = s0;
        if (is_curved && s1 >= 0) d2 = s1;
        auto rdbool = [&](const void* p, int i) -> bool {
            return bool_is_byte ? (((const uint8_t*)p)[i] != 0)
                                : (((const int*)p)[i] != 0);
        };
        const bool use0 = (!rdbool(VisCont, tv0)) && (d0 >= 0);
        const bool use1 = (!rdbool(VisCont, tv1)) && (d1 >= 0);
        const bool use2 = (!rdbool(VisCont, tv2)) && (d2 >= 0);
        const float4* c0p = (const float4*)(use0 ? &Vdisc[(size_t)d0 * NF] : &Vcont[(size_t)tv0 * NF]);
        const float4* c1p = (const float4*)(use1 ? &Vdisc[(size_t)d1 * NF] : &Vcont[(size_t)tv1 * NF]);
        const float4* c2p = (const float4*)(use2 ? &Vdisc[(size_t)d2 * NF] : &Vcont[(size_t)tv2 * NF]);
        c0a = c0p[0]; c0b = c0p[1];
        c1a = c1p[0]; c1b = c1p[1];
        c2a = c2p[0]; c2b = c2p[1];
        cf = 0.0f;
        if (is_curved) cf = rdbool(Tsign, cid) ? bub : -bub;
        const float4* cvp = (const float4*)&Vcurv[(size_t)cid * NF];
        cva = cvp[0]; cvb = cvp[1];
    }

    float feat[NF];
    {
        const float* a0 = (const float*)&c0a;  const float* bb0 = (const float*)&c0b;
        const float* a1 = (const float*)&c1a;  const float* bb1 = (const float*)&c1b;
        const float* a2 = (const float*)&c2a;  const float* bb2 = (const float*)&c2b;
        const float* av = (const float*)&cva;  const float* bv  = (const float*)&cvb;
#pragma unroll
        for (int f = 0; f < 4; ++f) {
            feat[f]     = w0 * a0[f]  + u * a1[f]  + v * a2[f]  + cf * av[f];
            feat[f + 4] = w0 * bb0[f] + u * bb1[f] + v * bb2[f] + cf * bv[f];
        }
    }

    unsigned pf[4];
#pragma unroll
    for (int i = 0; i < 4; ++i)
        pf[i] = (unsigned)f2bf(feat[2 * i]) | ((unsigned)f2bf(feat[2 * i + 1]) << 16);

    __syncthreads();   // slds ready

    // epilogue-table base with the only runtime term (hb) folded in once
    const float4* epb = (const float4*)&slds[NWSF_W] + (hb ? 4 : 0);

    // ---- half A: queries 0..31 ----
    float pA0 = 0.f, pA1 = 0.f, pA2 = 0.f;
    mlp_block(pf, hb, lane, slds, epb, pA0, pA1, pA2);

    // ---- half B: queries 32..63 ----
    unsigned pfx[4];
#pragma unroll
    for (int i = 0; i < 4; ++i) pfx[i] = (unsigned)__shfl_xor((int)pf[i], 32);
    float pB0 = 0.f, pB1 = 0.f, pB2 = 0.f;
    mlp_block(pfx, hb, lane, slds, epb, pB0, pB1, pB2);

    // ---- combine (validated r4/r6 epilogue) ----
    const float sA0 = pA0 + __shfl_xor(pA0, 32);
    const float sA1 = pA1 + __shfl_xor(pA1, 32);
    const float sA2 = pA2 + __shfl_xor(pA2, 32);
    const float sB0 = pB0 + __shfl_xor(pB0, 32);
    const float sB1 = pB1 + __shfl_xor(pB1, 32);
    const float sB2 = pB2 + __shfl_xor(pB2, 32);

    const float o0 = (lo_half ? sA0 : sB0) + b3[0];
    const float o1 = (lo_half ? sA1 : sB1) + b3[1];
    const float o2 = (lo_half ? sA2 : sB2) + b3[2];

    if (q < Q_NUM) {
        const size_t off = (size_t)q * NOUT;
        out[off + 0] = o0;
        out[off + 1] = o1;
        out[off + 2] = o2;
    }
}

extern "C" void kernel_launch(void* const* d_in, const int* in_sizes, int n_in,
                              void* d_out, int out_size, void* d_ws, size_t ws_size,
                              hipStream_t stream) {
    const float* QT_uv  = (const float*)d_in[2];
    const float* Vcont  = (const float*)d_in[3];
    const float* Vdisc  = (const float*)d_in[4];
    const float* Vcurv  = (const float*)d_in[5];
    const float* w1     = (const float*)d_in[6];
    const float* b1     = (const float*)d_in[7];
    const float* w2     = (const float*)d_in[8];
    const float* b2     = (const float*)d_in[9];
    const float* w3     = (const float*)d_in[10];
    const float* b3     = (const float*)d_in[11];
    const int*   T      = (const int*)d_in[12];
    const int*   QT_idx = (const int*)d_in[13];
    const void*  VisC   = d_in[14];
    const int*   Tadj   = (const int*)d_in[15];
    const void*  Tsign  = d_in[16];
    const int*   seco   = (const int*)d_in[17];
    float* out = (float*)d_out;

    unsigned* wsf = (unsigned*)d_ws;
    prep_w<<<1, 64, 0, stream>>>(w1, b1, w2, b2, w3, wsf);

    const int block = 256;
    const int grid  = (Q_NUM + block - 1) / block;

    if (ws_size >= WS_NEEDED) {
        float4* rec = (float4*)((char*)d_ws + WS_REC_OFF);
        build_rec<<<(T_NUM + 255) / 256, 256, 0, stream>>>(Vcont, Vdisc, Vcurv,
                                                           T, VisC, Tadj, Tsign, seco, rec);
        dann_fwd_t<true><<<grid, block, 0, stream>>>(QT_uv, Vcont, Vdisc, Vcurv,
                                                     b3, T, QT_idx, VisC, Tadj, Tsign, seco,
                                                     wsf, rec, out);
    } else {
        dann_fwd_t<false><<<grid, block, 0, stream>>>(QT_uv, Vcont, Vdisc, Vcurv,
                                                      b3, T, QT_idx, VisC, Tadj, Tsign, seco,
                                                      wsf, (const float4*)nullptr, out);
    }
}